// Round 20
// baseline (322.923 us; speedup 1.0000x reference)
//
#include <hip/hip_runtime.h>
#include <stdint.h>

typedef __bf16 bf16x8 __attribute__((ext_vector_type(8)));
typedef float f32x4 __attribute__((ext_vector_type(4)));

#define DEV __device__ __forceinline__
#define CAST_G(p) (const __attribute__((address_space(1))) unsigned int*)(p)
#define CAST_L(p) (__attribute__((address_space(3))) unsigned int*)(p)

constexpr int SEQ = 2048;
constexpr int DIM = 2048;
constexpr int NH  = 16;
constexpr int DK  = 128;
constexpr int BATCH = 2;
constexpr size_t TSZ = (size_t)BATCH * SEQ * DIM;   // 8388608 elements
constexpr size_t WSZ = (size_t)DIM * DIM;           // 4194304 elements per weight
constexpr float ATTN_SCALE = 0.08838834764831845f;  // 1/sqrt(128)

DEV unsigned short f2bf(float f) {
  unsigned int u = __float_as_uint(f);
  unsigned int r = (u + 0x7fffu + ((u >> 16) & 1u)) >> 16;
  return (unsigned short)r;
}

// ---------------------------------------------------------------------------
// fp32 -> bf16 (RTNE), 8 elements/thread, vectorized.
// ---------------------------------------------------------------------------
__global__ __launch_bounds__(256)
void cvt_f32_bf16(const float* __restrict__ src, unsigned short* __restrict__ dst,
                  int n8) {
  int i = blockIdx.x * 256 + threadIdx.x;
  if (i >= n8) return;
  float4 a = *reinterpret_cast<const float4*>(src + (size_t)i * 8);
  float4 b = *reinterpret_cast<const float4*>(src + (size_t)i * 8 + 4);
  unsigned short o[8];
  o[0] = f2bf(a.x); o[1] = f2bf(a.y); o[2] = f2bf(a.z); o[3] = f2bf(a.w);
  o[4] = f2bf(b.x); o[5] = f2bf(b.y); o[6] = f2bf(b.z); o[7] = f2bf(b.w);
  *reinterpret_cast<uint4*>(dst + (size_t)i * 8) = *reinterpret_cast<const uint4*>(o);
}

// Batched 3-weight conversion (z selects source/dest).
__global__ __launch_bounds__(256)
void cvt3_f32_bf16(const float* __restrict__ s0, const float* __restrict__ s1,
                   const float* __restrict__ s2,
                   unsigned short* __restrict__ d0, unsigned short* __restrict__ d1,
                   unsigned short* __restrict__ d2, int n8) {
  const float* src = (blockIdx.z == 0) ? s0 : (blockIdx.z == 1) ? s1 : s2;
  unsigned short* dst = (blockIdx.z == 0) ? d0 : (blockIdx.z == 1) ? d1 : d2;
  int i = blockIdx.x * 256 + threadIdx.x;
  if (i >= n8) return;
  float4 a = *reinterpret_cast<const float4*>(src + (size_t)i * 8);
  float4 b = *reinterpret_cast<const float4*>(src + (size_t)i * 8 + 4);
  unsigned short o[8];
  o[0] = f2bf(a.x); o[1] = f2bf(a.y); o[2] = f2bf(a.z); o[3] = f2bf(a.w);
  o[4] = f2bf(b.x); o[5] = f2bf(b.y); o[6] = f2bf(b.z); o[7] = f2bf(b.w);
  *reinterpret_cast<uint4*>(dst + (size_t)i * 8) = *reinterpret_cast<const uint4*>(o);
}

// ---------------------------------------------------------------------------
// Shared GEMM core: C[M,Nc] = A[M,K] * W[Nc,K]^T (row-major, bf16, fp32 acc)
// 128x128 tile, BK=64, 4 waves (2x2).  Staging via global_load_lds(16B) with
// PRE-SWIZZLED SOURCE (involution c8^=(r&7)); LDS dest linear; reads XOR'd.
// ---------------------------------------------------------------------------
DEV void gemm_core(const unsigned short* __restrict__ A,
                   const unsigned short* __restrict__ W,
                   unsigned short* As, unsigned short* Bs,
                   int row0, int col0, int t, int wid, int wr, int wc,
                   int l16, int lg, f32x4 (&acc)[4][4]) {
  const int srow = t >> 3;                         // 0..31
  const int scol = ((t & 7) ^ (srow & 7)) << 3;    // pre-swizzled src elem off
  const unsigned short* Asrc = A + (size_t)(row0 + srow) * DIM + scol;
  const unsigned short* Wsrc = W + (size_t)(col0 + srow) * DIM + scol;

  for (int k0 = 0; k0 < DIM; k0 += 64) {
    __syncthreads();
#pragma unroll
    for (int i = 0; i < 4; ++i) {
      __builtin_amdgcn_global_load_lds(CAST_G(Asrc + (size_t)i * 32 * DIM + k0),
                                       CAST_L(As + i * 2048 + wid * 512), 16, 0, 0);
      __builtin_amdgcn_global_load_lds(CAST_G(Wsrc + (size_t)i * 32 * DIM + k0),
                                       CAST_L(Bs + i * 2048 + wid * 512), 16, 0, 0);
    }
    __syncthreads();
#pragma unroll
    for (int ks = 0; ks < 2; ++ks) {
      bf16x8 af[4], bfr[4];
#pragma unroll
      for (int i = 0; i < 4; ++i) {
        int ra = wr + i * 16 + l16;
        af[i] = *reinterpret_cast<const bf16x8*>(&As[ra * 64 + (((ks * 4 + lg) ^ (ra & 7)) << 3)]);
        int rb = wc + i * 16 + l16;
        bfr[i] = *reinterpret_cast<const bf16x8*>(&Bs[rb * 64 + (((ks * 4 + lg) ^ (rb & 7)) << 3)]);
      }
#pragma unroll
      for (int i = 0; i < 4; ++i)
#pragma unroll
        for (int j = 0; j < 4; ++j)
          acc[i][j] = __builtin_amdgcn_mfma_f32_16x16x32_bf16(af[i], bfr[j], acc[i][j], 0, 0, 0);
    }
  }
}

// ---------------------------------------------------------------------------
// Merged QKV projection: blockIdx.z selects {wq,wk,wv}.
// z=0: RoPE -> scatter bf16 Q.  z=1: RoPE -> scatter f32 K + bf16 K.
// z=2: scatter f32 V.
// ---------------------------------------------------------------------------
__global__ __launch_bounds__(256, 2)
void gemm_qkv(const unsigned short* __restrict__ A,
              const unsigned short* __restrict__ W0,
              const unsigned short* __restrict__ W1,
              const unsigned short* __restrict__ W2,
              unsigned short* __restrict__ Qb,
              unsigned short* __restrict__ Kb,
              float* __restrict__ Kf,
              float* __restrict__ Vf) {
  __shared__ __align__(16) unsigned short As[128 * 64];
  __shared__ __align__(16) unsigned short Bs[128 * 64];

  const int t = threadIdx.x;
  const int lane = t & 63;
  const int wid = t >> 6;
  const int wr = (wid >> 1) << 6;
  const int wc = (wid & 1) << 6;
  const int l16 = lane & 15, lg = lane >> 4;
  const int row0 = blockIdx.y * 128;
  const int col0 = blockIdx.x * 128;
  const int z = blockIdx.z;
  const unsigned short* W = (z == 0) ? W0 : ((z == 1) ? W1 : W2);

  f32x4 acc[4][4] = {};
  gemm_core(A, W, As, Bs, row0, col0, t, wid, wr, wc, l16, lg, acc);

#pragma unroll
  for (int j = 0; j < 4; ++j) {
    int colg = col0 + wc + j * 16 + l16;
    int jj = (colg >> 1) & 63;
    float invf = __expf((float)jj * -0.14391156831212787f);  // 10000^(-jj/64)
#pragma unroll
    for (int i = 0; i < 4; ++i) {
#pragma unroll
      for (int r = 0; r < 4; ++r) {
        int rowg = row0 + wr + i * 16 + lg * 4 + r;
        float v = acc[i][j][r];
        float outv;
        if (z < 2) {
          float p = __shfl_xor(v, 1, 64);
          int pos = rowg & (SEQ - 1);
          float ang = (float)pos * invf;
          float sn, cs;
          __sincosf(ang, &sn, &cs);
          outv = (colg & 1) ? fmaf(p, sn, v * cs) : fmaf(v, cs, -(p * sn));
        } else {
          outv = v;
        }
        int b = rowg >> 11, pos = rowg & (SEQ - 1);
        int h = colg >> 7, d = colg & (DK - 1);
        size_t idx = (((size_t)(b * NH + h)) * SEQ + pos) * DK + d;
        if (z == 0) Qb[idx] = f2bf(outv);
        else if (z == 1) { Kf[idx] = outv; Kb[idx] = f2bf(outv); }
        else Vf[idx] = outv;
      }
    }
  }
}

// ---------------------------------------------------------------------------
// WO projection: plain row-major f32 store.
// ---------------------------------------------------------------------------
__global__ __launch_bounds__(256, 2)
void gemm_wo(const unsigned short* __restrict__ A,
             const unsigned short* __restrict__ W,
             float* __restrict__ Df) {
  __shared__ __align__(16) unsigned short As[128 * 64];
  __shared__ __align__(16) unsigned short Bs[128 * 64];

  const int t = threadIdx.x;
  const int lane = t & 63;
  const int wid = t >> 6;
  const int wr = (wid >> 1) << 6;
  const int wc = (wid & 1) << 6;
  const int l16 = lane & 15, lg = lane >> 4;
  const int row0 = blockIdx.y * 128;
  const int col0 = blockIdx.x * 128;

  f32x4 acc[4][4] = {};
  gemm_core(A, W, As, Bs, row0, col0, t, wid, wr, wc, l16, lg, acc);

#pragma unroll
  for (int i = 0; i < 4; ++i)
#pragma unroll
    for (int j = 0; j < 4; ++j) {
      int colg = col0 + wc + j * 16 + l16;
#pragma unroll
      for (int r = 0; r < 4; ++r) {
        int rowg = row0 + wr + i * 16 + lg * 4 + r;
        Df[(size_t)rowg * DIM + colg] = acc[i][j][r];
      }
    }
}

// ---------------------------------------------------------------------------
// V^T builder: V [B,H,S,DK] f32 -> VT [B,H,DK,S] bf16
// ---------------------------------------------------------------------------
__global__ __launch_bounds__(256, 2)
void vtrans(const float* __restrict__ V, unsigned short* __restrict__ VT) {
  __shared__ float vs[64 * 128];  // 32KB [pos][d]
  const int t = threadIdx.x;
  const int bh = blockIdx.y;
  const int p0 = blockIdx.x * 64;
  const float* src = V + ((size_t)bh * SEQ + p0) * DK;
#pragma unroll
  for (int s = 0; s < 8; ++s) {
    int id = s * 256 + t;
    *reinterpret_cast<float4*>(&vs[id * 4]) = *reinterpret_cast<const float4*>(&src[id * 4]);
  }
  __syncthreads();
  const int w = t >> 6, l = t & 63;
  unsigned short* dstb = VT + (size_t)bh * DK * SEQ + p0;
#pragma unroll
  for (int it = 0; it < 4; ++it) {
    int d = w * 32 + (it & 1) * 16 + (l & 15);
    int kc = (it >> 1) * 4 + (l >> 4);
    unsigned short tmp[8];
#pragma unroll
    for (int j = 0; j < 8; ++j) tmp[j] = f2bf(vs[(kc * 8 + j) * DK + d]);
    *reinterpret_cast<uint4*>(&dstb[(size_t)d * SEQ + kc * 8]) =
        *reinterpret_cast<const uint4*>(tmp);
  }
}

// ---------------------------------------------------------------------------
// Fused causal flash attention — r16 structure with KVBLK=64 (LDS 80KB ->
// 2 blocks/CU for cross-block latency hiding).  512 thr / 8 waves, one
// block per (bh, pair).  Pair {15-pj, pj}: 34 stage-iters of 64 keys per
// block (balanced).  Grid (bh=32, pj=8): lin%8 = bh%8 -> XCD locality.
// ---------------------------------------------------------------------------
struct __align__(16) AttnSmem {
  unsigned short Qs[128 * 128];   // 32KB  [q][dk], swizzled
  unsigned short Ks[64 * 128];    // 16KB  [key][dk], swizzled  (epilogue reuse)
  unsigned short Vts[128 * 64];   // 16KB  [d][key], swizzled   (epilogue reuse)
  unsigned short Ps[8 * 16 * 64]; // 16KB  per-wave P [16 q][64 key], swizzled
};

__global__ __launch_bounds__(512, 2)
void attn_fused(const unsigned short* __restrict__ Q,
                const unsigned short* __restrict__ K,
                const unsigned short* __restrict__ VT,
                unsigned short* __restrict__ AO) {
  __shared__ AttnSmem sm;
  const int t = threadIdx.x;          // 0..511
  const int lane = t & 63;
  const int wid = t >> 6;             // 0..7
  const int l16 = lane & 15, lg = lane >> 4;
  const int bh = blockIdx.x;          // 0..31  (lin%8 = bh%8 -> XCD locality)
  const int pj = blockIdx.y;          // 0..7 pair id
  const int b = bh >> 4, h = bh & 15;

  const unsigned short* Kbase = K + (size_t)bh * SEQ * DK;
  const unsigned short* VTbase = VT + (size_t)bh * DK * SEQ;

  for (int half = 0; half < 2; ++half) {
    const int qt = half ? pj : (15 - pj);
    const int q0 = qt * 128;
    const int nst = 2 * (qt + 1);     // 64-key stage-iters
    const unsigned short* Qbase = Q + ((size_t)bh * SEQ + q0) * DK;

    // stage Q tile [128][128]: 16 chunks/row, swizzle c^(r&7)
#pragma unroll
    for (int s = 0; s < 4; ++s) {
      int id = s * 512 + t;
      int r = id >> 4, c = id & 15;
      uint4 v = *reinterpret_cast<const uint4*>(Qbase + (size_t)r * DK + (c << 3));
      *reinterpret_cast<uint4*>(&sm.Qs[r * 128 + ((c ^ (r & 7)) << 3)]) = v;
    }

    f32x4 accO[8] = {};
    float mrun[4], lrun[4];
#pragma unroll
    for (int r = 0; r < 4; ++r) { mrun[r] = -INFINITY; lrun[r] = 0.f; }

    uint4 pk[2], pv[2];
#pragma unroll
    for (int s = 0; s < 2; ++s) {
      int id = s * 512 + t;
      int rk = id >> 4, ck = id & 15;
      pk[s] = *reinterpret_cast<const uint4*>(Kbase + (size_t)rk * DK + (ck << 3));
      int rv = id >> 3, cv = id & 7;
      pv[s] = *reinterpret_cast<const uint4*>(VTbase + (size_t)rv * SEQ + (cv << 3));
    }

    for (int kt = 0; kt < nst; ++kt) {
      const int key0 = kt * 64;
      __syncthreads();
#pragma unroll
      for (int s = 0; s < 2; ++s) {
        int id = s * 512 + t;
        int rk = id >> 4, ck = id & 15;
        *reinterpret_cast<uint4*>(&sm.Ks[rk * 128 + ((ck ^ (rk & 7)) << 3)]) = pk[s];
        int rv = id >> 3, cv = id & 7;
        *reinterpret_cast<uint4*>(&sm.Vts[rv * 64 + ((cv ^ (rv & 7)) << 3)]) = pv[s];
      }
      __syncthreads();
      if (kt + 1 < nst) {
        const int kn = key0 + 64;
#pragma unroll
        for (int s = 0; s < 2; ++s) {
          int id = s * 512 + t;
          int rk = id >> 4, ck = id & 15;
          pk[s] = *reinterpret_cast<const uint4*>(Kbase + (size_t)(kn + rk) * DK + (ck << 3));
          int rv = id >> 3, cv = id & 7;
          pv[s] = *reinterpret_cast<const uint4*>(VTbase + (size_t)rv * SEQ + kn + (cv << 3));
        }
      }

      // ---- S = Q K^T  (16 q-rows per wave) ------------------------------
      f32x4 sf[4] = {};
      __builtin_amdgcn_s_setprio(1);
#pragma unroll
      for (int ks = 0; ks < 4; ++ks) {
        int ra = wid * 16 + l16;
        bf16x8 aq = *reinterpret_cast<const bf16x8*>(
            &sm.Qs[ra * 128 + (((ks * 4 + lg) ^ (ra & 7)) << 3)]);
#pragma unroll
        for (int nj = 0; nj < 4; ++nj) {
          int rb = nj * 16 + l16;
          bf16x8 bk = *reinterpret_cast<const bf16x8*>(
              &sm.Ks[rb * 128 + (((ks * 4 + lg) ^ (rb & 7)) << 3)]);
          sf[nj] = __builtin_amdgcn_mfma_f32_16x16x32_bf16(aq, bk, sf[nj], 0, 0, 0);
        }
      }
      __builtin_amdgcn_s_setprio(0);

      // ---- scale + causal mask ------------------------------------------
      const int qwbase = q0 + wid * 16;
      const bool need_mask = (key0 + 63) > qwbase;
#pragma unroll
      for (int nj = 0; nj < 4; ++nj) {
        int kcol = key0 + nj * 16 + l16;
#pragma unroll
        for (int r = 0; r < 4; ++r) {
          float v = sf[nj][r] * ATTN_SCALE;
          if (need_mask) {
            int qrow = qwbase + lg * 4 + r;
            if (kcol > qrow) v = -INFINITY;
          }
          sf[nj][r] = v;
        }
      }

      // ---- online softmax -----------------------------------------------
      float alpha[4];
#pragma unroll
      for (int r = 0; r < 4; ++r) {
        float m0 = fmaxf(fmaxf(sf[0][r], sf[1][r]), fmaxf(sf[2][r], sf[3][r]));
#pragma unroll
        for (int off = 1; off < 16; off <<= 1)
          m0 = fmaxf(m0, __shfl_xor(m0, off, 64));
        float mn = fmaxf(mrun[r], m0);
        alpha[r] = __expf(mrun[r] - mn);   // exp(-inf)=0 on first tile
        mrun[r] = mn;
      }
      float rs[4] = {0.f, 0.f, 0.f, 0.f};
#pragma unroll
      for (int nj = 0; nj < 4; ++nj) {
        int colb = nj * 16 + l16;
        int ch = colb >> 3, cb = colb & 7;
#pragma unroll
        for (int r = 0; r < 4; ++r) {
          float p = __expf(sf[nj][r] - mrun[r]);
          rs[r] += p;
          int prow = lg * 4 + r;
          sm.Ps[wid * 1024 + prow * 64 + ((ch ^ (prow & 7)) << 3) + cb] = f2bf(p);
        }
      }
#pragma unroll
      for (int r = 0; r < 4; ++r) {
        float s0 = rs[r];
#pragma unroll
        for (int off = 1; off < 16; off <<= 1)
          s0 += __shfl_xor(s0, off, 64);
        lrun[r] = lrun[r] * alpha[r] + s0;
      }
#pragma unroll
      for (int dj = 0; dj < 8; ++dj)
#pragma unroll
        for (int r = 0; r < 4; ++r) accO[dj][r] *= alpha[r];

      // ---- PV -----------------------------------------------------------
      __builtin_amdgcn_s_setprio(1);
#pragma unroll
      for (int ks = 0; ks < 2; ++ks) {
        bf16x8 ap = *reinterpret_cast<const bf16x8*>(
            &sm.Ps[wid * 1024 + l16 * 64 + (((ks * 4 + lg) ^ (l16 & 7)) << 3)]);
#pragma unroll
        for (int dj = 0; dj < 8; ++dj) {
          int rv = dj * 16 + l16;
          bf16x8 bv = *reinterpret_cast<const bf16x8*>(
              &sm.Vts[rv * 64 + (((ks * 4 + lg) ^ (rv & 7)) << 3)]);
          accO[dj] = __builtin_amdgcn_mfma_f32_16x16x32_bf16(ap, bv, accO[dj], 0, 0, 0);
        }
      }
      __builtin_amdgcn_s_setprio(0);
    }

    // ---- epilogue: per-wave 16x128 transpose in (dead) Ks+Vts region ----
    __syncthreads();   // all waves done reading Ks/Vts
    unsigned short* Pw = sm.Ks + wid * 2048;   // 8 x 4KB spans Ks(16K)+Vts(16K)
    float inv[4];
#pragma unroll
    for (int r = 0; r < 4; ++r) inv[r] = 1.0f / lrun[r];
#pragma unroll
    for (int dj = 0; dj < 8; ++dj)
#pragma unroll
      for (int r = 0; r < 4; ++r)
        Pw[(lg * 4 + r) * 128 + dj * 16 + l16] = f2bf(accO[dj][r] * inv[r]);
    // same-wave write->read; compiler inserts lgkmcnt
#pragma unroll
    for (int ps = 0; ps < 4; ++ps) {
      int row = ps * 4 + lg;               // 0..15
      uint4 v = *reinterpret_cast<const uint4*>(&Pw[row * 128 + l16 * 8]);
      int qpos = q0 + wid * 16 + row;
      *reinterpret_cast<uint4*>(
          &AO[((size_t)(b * SEQ + qpos)) * DIM + h * DK + l16 * 8]) = v;
    }
    __syncthreads();   // protect Ks/Vts before next half restages
  }
}

// ---------------------------------------------------------------------------
extern "C" void kernel_launch(void* const* d_in, const int* in_sizes, int n_in,
                              void* d_out, int out_size, void* d_ws, size_t ws_size,
                              hipStream_t stream) {
  const float* x  = (const float*)d_in[0];
  const float* wq = (const float*)d_in[1];
  const float* wk = (const float*)d_in[2];
  const float* wv = (const float*)d_in[3];
  const float* wo = (const float*)d_in[4];

  // Outputs are FLOAT32: out [B,S,DIM], K [B,H,S,DK], V [B,H,S,DK].
  float* outF = (float*)d_out;
  float* outK = outF + TSZ;
  float* outV = outF + 2 * TSZ;

  // bf16 Q/K copies live in the (dead until final GEMM) out[0] f32 slot.
  unsigned short* qb = (unsigned short*)outF;
  unsigned short* kb = qb + TSZ;

  // ws (bf16 elems), total 2*TSZ + WSZ = 41.9 MB (proven footprint):
  unsigned short* xb  = (unsigned short*)d_ws;
  unsigned short* aop = xb + TSZ;
  unsigned short* wb  = xb + 2 * TSZ;
  unsigned short* wkb = aop;                    // first half of aop
  unsigned short* wvb = aop + WSZ;              // second half of aop
  unsigned short* vtb = xb;                     // VT over xb (x dead post-QKV)

  dim3 blk(256);
  const int cvtW = (int)(WSZ / 2048), n8W = (int)(WSZ / 8);

  cvt_f32_bf16<<<dim3((int)(TSZ / 2048)), blk, 0, stream>>>(x, xb, (int)(TSZ / 8));
  cvt3_f32_bf16<<<dim3(cvtW, 1, 3), blk, 0, stream>>>(wq, wk, wv, wb, wkb, wvb, n8W);

  gemm_qkv<<<dim3(16, 32, 3), blk, 0, stream>>>(xb, wb, wkb, wvb,
                                                qb, kb, outK, outV);

  vtrans<<<dim3(32, 32), blk, 0, stream>>>(outV, vtb);                // VT bf16

  attn_fused<<<dim3(32, 8), dim3(512), 0, stream>>>(qb, kb, vtb, aop);

  cvt_f32_bf16<<<dim3(cvtW), blk, 0, stream>>>(wo, wb, n8W);
  gemm_wo<<<dim3(16, 32), blk, 0, stream>>>(aop, wb, outF);           // final f32
}

// Round 21
// 322.656 us; speedup vs baseline: 1.0008x; 1.0008x over previous
//
#include <hip/hip_runtime.h>
#include <stdint.h>

typedef __bf16 bf16x8 __attribute__((ext_vector_type(8)));
typedef float f32x4 __attribute__((ext_vector_type(4)));

#define DEV __device__ __forceinline__
#define CAST_G(p) (const __attribute__((address_space(1))) unsigned int*)(p)
#define CAST_L(p) (__attribute__((address_space(3))) unsigned int*)(p)

constexpr int SEQ = 2048;
constexpr int DIM = 2048;
constexpr int NH  = 16;
constexpr int DK  = 128;
constexpr int BATCH = 2;
constexpr size_t TSZ = (size_t)BATCH * SEQ * DIM;   // 8388608 elements
constexpr size_t WSZ = (size_t)DIM * DIM;           // 4194304 elements per weight
constexpr float ATTN_SCALE = 0.08838834764831845f;  // 1/sqrt(128)

DEV unsigned short f2bf(float f) {
  unsigned int u = __float_as_uint(f);
  unsigned int r = (u + 0x7fffu + ((u >> 16) & 1u)) >> 16;
  return (unsigned short)r;
}

// ---------------------------------------------------------------------------
// fp32 -> bf16 (RTNE), 8 elements/thread, vectorized.
// ---------------------------------------------------------------------------
__global__ __launch_bounds__(256)
void cvt_f32_bf16(const float* __restrict__ src, unsigned short* __restrict__ dst,
                  int n8) {
  int i = blockIdx.x * 256 + threadIdx.x;
  if (i >= n8) return;
  float4 a = *reinterpret_cast<const float4*>(src + (size_t)i * 8);
  float4 b = *reinterpret_cast<const float4*>(src + (size_t)i * 8 + 4);
  unsigned short o[8];
  o[0] = f2bf(a.x); o[1] = f2bf(a.y); o[2] = f2bf(a.z); o[3] = f2bf(a.w);
  o[4] = f2bf(b.x); o[5] = f2bf(b.y); o[6] = f2bf(b.z); o[7] = f2bf(b.w);
  *reinterpret_cast<uint4*>(dst + (size_t)i * 8) = *reinterpret_cast<const uint4*>(o);
}

// Batched 3-weight conversion (z selects source/dest).
__global__ __launch_bounds__(256)
void cvt3_f32_bf16(const float* __restrict__ s0, const float* __restrict__ s1,
                   const float* __restrict__ s2,
                   unsigned short* __restrict__ d0, unsigned short* __restrict__ d1,
                   unsigned short* __restrict__ d2, int n8) {
  const float* src = (blockIdx.z == 0) ? s0 : (blockIdx.z == 1) ? s1 : s2;
  unsigned short* dst = (blockIdx.z == 0) ? d0 : (blockIdx.z == 1) ? d1 : d2;
  int i = blockIdx.x * 256 + threadIdx.x;
  if (i >= n8) return;
  float4 a = *reinterpret_cast<const float4*>(src + (size_t)i * 8);
  float4 b = *reinterpret_cast<const float4*>(src + (size_t)i * 8 + 4);
  unsigned short o[8];
  o[0] = f2bf(a.x); o[1] = f2bf(a.y); o[2] = f2bf(a.z); o[3] = f2bf(a.w);
  o[4] = f2bf(b.x); o[5] = f2bf(b.y); o[6] = f2bf(b.z); o[7] = f2bf(b.w);
  *reinterpret_cast<uint4*>(dst + (size_t)i * 8) = *reinterpret_cast<const uint4*>(o);
}

// ---------------------------------------------------------------------------
// Shared GEMM core: C[M,Nc] = A[M,K] * W[Nc,K]^T (row-major, bf16, fp32 acc)
// 128x128 tile, BK=64, 4 waves (2x2).  Staging via global_load_lds(16B) with
// PRE-SWIZZLED SOURCE (involution c8^=(r&7)); LDS dest linear; reads XOR'd.
// ---------------------------------------------------------------------------
DEV void gemm_core(const unsigned short* __restrict__ A,
                   const unsigned short* __restrict__ W,
                   unsigned short* As, unsigned short* Bs,
                   int row0, int col0, int t, int wid, int wr, int wc,
                   int l16, int lg, f32x4 (&acc)[4][4]) {
  const int srow = t >> 3;                         // 0..31
  const int scol = ((t & 7) ^ (srow & 7)) << 3;    // pre-swizzled src elem off
  const unsigned short* Asrc = A + (size_t)(row0 + srow) * DIM + scol;
  const unsigned short* Wsrc = W + (size_t)(col0 + srow) * DIM + scol;

  for (int k0 = 0; k0 < DIM; k0 += 64) {
    __syncthreads();
#pragma unroll
    for (int i = 0; i < 4; ++i) {
      __builtin_amdgcn_global_load_lds(CAST_G(Asrc + (size_t)i * 32 * DIM + k0),
                                       CAST_L(As + i * 2048 + wid * 512), 16, 0, 0);
      __builtin_amdgcn_global_load_lds(CAST_G(Wsrc + (size_t)i * 32 * DIM + k0),
                                       CAST_L(Bs + i * 2048 + wid * 512), 16, 0, 0);
    }
    __syncthreads();
#pragma unroll
    for (int ks = 0; ks < 2; ++ks) {
      bf16x8 af[4], bfr[4];
#pragma unroll
      for (int i = 0; i < 4; ++i) {
        int ra = wr + i * 16 + l16;
        af[i] = *reinterpret_cast<const bf16x8*>(&As[ra * 64 + (((ks * 4 + lg) ^ (ra & 7)) << 3)]);
        int rb = wc + i * 16 + l16;
        bfr[i] = *reinterpret_cast<const bf16x8*>(&Bs[rb * 64 + (((ks * 4 + lg) ^ (rb & 7)) << 3)]);
      }
#pragma unroll
      for (int i = 0; i < 4; ++i)
#pragma unroll
        for (int j = 0; j < 4; ++j)
          acc[i][j] = __builtin_amdgcn_mfma_f32_16x16x32_bf16(af[i], bfr[j], acc[i][j], 0, 0, 0);
    }
  }
}

// ---------------------------------------------------------------------------
// Merged QKV projection: blockIdx.z selects {wq,wk,wv}.
// z=0: RoPE -> scatter bf16 Q.  z=1: RoPE -> scatter f32 K + bf16 K.
// z=2: scatter f32 V.
// ---------------------------------------------------------------------------
__global__ __launch_bounds__(256, 2)
void gemm_qkv(const unsigned short* __restrict__ A,
              const unsigned short* __restrict__ W0,
              const unsigned short* __restrict__ W1,
              const unsigned short* __restrict__ W2,
              unsigned short* __restrict__ Qb,
              unsigned short* __restrict__ Kb,
              float* __restrict__ Kf,
              float* __restrict__ Vf) {
  __shared__ __align__(16) unsigned short As[128 * 64];
  __shared__ __align__(16) unsigned short Bs[128 * 64];

  const int t = threadIdx.x;
  const int lane = t & 63;
  const int wid = t >> 6;
  const int wr = (wid >> 1) << 6;
  const int wc = (wid & 1) << 6;
  const int l16 = lane & 15, lg = lane >> 4;
  const int row0 = blockIdx.y * 128;
  const int col0 = blockIdx.x * 128;
  const int z = blockIdx.z;
  const unsigned short* W = (z == 0) ? W0 : ((z == 1) ? W1 : W2);

  f32x4 acc[4][4] = {};
  gemm_core(A, W, As, Bs, row0, col0, t, wid, wr, wc, l16, lg, acc);

#pragma unroll
  for (int j = 0; j < 4; ++j) {
    int colg = col0 + wc + j * 16 + l16;
    int jj = (colg >> 1) & 63;
    float invf = __expf((float)jj * -0.14391156831212787f);  // 10000^(-jj/64)
#pragma unroll
    for (int i = 0; i < 4; ++i) {
#pragma unroll
      for (int r = 0; r < 4; ++r) {
        int rowg = row0 + wr + i * 16 + lg * 4 + r;
        float v = acc[i][j][r];
        float outv;
        if (z < 2) {
          float p = __shfl_xor(v, 1, 64);
          int pos = rowg & (SEQ - 1);
          float ang = (float)pos * invf;
          float sn, cs;
          __sincosf(ang, &sn, &cs);
          outv = (colg & 1) ? fmaf(p, sn, v * cs) : fmaf(v, cs, -(p * sn));
        } else {
          outv = v;
        }
        int b = rowg >> 11, pos = rowg & (SEQ - 1);
        int h = colg >> 7, d = colg & (DK - 1);
        size_t idx = (((size_t)(b * NH + h)) * SEQ + pos) * DK + d;
        if (z == 0) Qb[idx] = f2bf(outv);
        else if (z == 1) { Kf[idx] = outv; Kb[idx] = f2bf(outv); }
        else Vf[idx] = outv;
      }
    }
  }
}

// ---------------------------------------------------------------------------
// WO projection: plain row-major f32 store.
// ---------------------------------------------------------------------------
__global__ __launch_bounds__(256, 2)
void gemm_wo(const unsigned short* __restrict__ A,
             const unsigned short* __restrict__ W,
             float* __restrict__ Df) {
  __shared__ __align__(16) unsigned short As[128 * 64];
  __shared__ __align__(16) unsigned short Bs[128 * 64];

  const int t = threadIdx.x;
  const int lane = t & 63;
  const int wid = t >> 6;
  const int wr = (wid >> 1) << 6;
  const int wc = (wid & 1) << 6;
  const int l16 = lane & 15, lg = lane >> 4;
  const int row0 = blockIdx.y * 128;
  const int col0 = blockIdx.x * 128;

  f32x4 acc[4][4] = {};
  gemm_core(A, W, As, Bs, row0, col0, t, wid, wr, wc, l16, lg, acc);

#pragma unroll
  for (int i = 0; i < 4; ++i)
#pragma unroll
    for (int j = 0; j < 4; ++j) {
      int colg = col0 + wc + j * 16 + l16;
#pragma unroll
      for (int r = 0; r < 4; ++r) {
        int rowg = row0 + wr + i * 16 + lg * 4 + r;
        Df[(size_t)rowg * DIM + colg] = acc[i][j][r];
      }
    }
}

// ---------------------------------------------------------------------------
// V^T builder: V [B,H,S,DK] f32 -> VT [B,H,DK,S] bf16
// ---------------------------------------------------------------------------
__global__ __launch_bounds__(256, 2)
void vtrans(const float* __restrict__ V, unsigned short* __restrict__ VT) {
  __shared__ float vs[64 * 128];  // 32KB [pos][d]
  const int t = threadIdx.x;
  const int bh = blockIdx.y;
  const int p0 = blockIdx.x * 64;
  const float* src = V + ((size_t)bh * SEQ + p0) * DK;
#pragma unroll
  for (int s = 0; s < 8; ++s) {
    int id = s * 256 + t;
    *reinterpret_cast<float4*>(&vs[id * 4]) = *reinterpret_cast<const float4*>(&src[id * 4]);
  }
  __syncthreads();
  const int w = t >> 6, l = t & 63;
  unsigned short* dstb = VT + (size_t)bh * DK * SEQ + p0;
#pragma unroll
  for (int it = 0; it < 4; ++it) {
    int d = w * 32 + (it & 1) * 16 + (l & 15);
    int kc = (it >> 1) * 4 + (l >> 4);
    unsigned short tmp[8];
#pragma unroll
    for (int j = 0; j < 8; ++j) tmp[j] = f2bf(vs[(kc * 8 + j) * DK + d]);
    *reinterpret_cast<uint4*>(&dstb[(size_t)d * SEQ + kc * 8]) =
        *reinterpret_cast<const uint4*>(tmp);
  }
}

// ---------------------------------------------------------------------------
// Fused causal flash attention — measured-best structure (152us).
// 512 thr / 8 waves, one block per (bh, pair).  Pair {15-pj, pj}: 17
// stage-iters of 128 keys per block (balanced).  Grid (bh=32, pj=8):
// lin%8 = bh%8 -> all pair-blocks of a bh share an XCD.  LDS 112KB.
// ---------------------------------------------------------------------------
struct __align__(16) AttnSmem {
  unsigned short Qs[128 * 128];   // 32KB  [q][dk], swizzled
  unsigned short Ks[128 * 128];   // 32KB  [key][dk], swizzled   (epilogue reuse)
  unsigned short Vts[128 * 128];  // 32KB  [d][key], swizzled
  unsigned short Ps[8 * 16 * 64]; // 16KB  per-wave P [16 q][64 key], swizzled
};

__global__ __launch_bounds__(512, 1)
void attn_fused(const unsigned short* __restrict__ Q,
                const unsigned short* __restrict__ K,
                const unsigned short* __restrict__ VT,
                unsigned short* __restrict__ AO) {
  __shared__ AttnSmem sm;
  const int t = threadIdx.x;          // 0..511
  const int lane = t & 63;
  const int wid = t >> 6;             // 0..7
  const int l16 = lane & 15, lg = lane >> 4;
  const int bh = blockIdx.x;          // 0..31  (lin%8 = bh%8 -> XCD locality)
  const int pj = blockIdx.y;          // 0..7 pair id
  const int b = bh >> 4, h = bh & 15;

  const unsigned short* Kbase = K + (size_t)bh * SEQ * DK;
  const unsigned short* VTbase = VT + (size_t)bh * DK * SEQ;

  for (int half = 0; half < 2; ++half) {
    const int qt = half ? pj : (15 - pj);
    const int q0 = qt * 128;
    const int nst = qt + 1;           // 128-key stage-iters
    const unsigned short* Qbase = Q + ((size_t)bh * SEQ + q0) * DK;

    // stage Q tile [128][128]: 16 chunks/row, swizzle c^(r&7)
#pragma unroll
    for (int s = 0; s < 4; ++s) {
      int id = s * 512 + t;
      int r = id >> 4, c = id & 15;
      uint4 v = *reinterpret_cast<const uint4*>(Qbase + (size_t)r * DK + (c << 3));
      *reinterpret_cast<uint4*>(&sm.Qs[r * 128 + ((c ^ (r & 7)) << 3)]) = v;
    }

    f32x4 accO[8] = {};
    float mrun[4], lrun[4];
#pragma unroll
    for (int r = 0; r < 4; ++r) { mrun[r] = -INFINITY; lrun[r] = 0.f; }

    uint4 pk[4], pv[4];
#pragma unroll
    for (int s = 0; s < 4; ++s) {
      int id = s * 512 + t;
      int rk = id >> 4, ck = id & 15;
      pk[s] = *reinterpret_cast<const uint4*>(Kbase + (size_t)rk * DK + (ck << 3));
      pv[s] = *reinterpret_cast<const uint4*>(VTbase + (size_t)rk * SEQ + (ck << 3));
    }

    for (int kt = 0; kt < nst; ++kt) {
      __syncthreads();
#pragma unroll
      for (int s = 0; s < 4; ++s) {
        int id = s * 512 + t;
        int rk = id >> 4, ck = id & 15;
        int sw = ((ck ^ (rk & 7)) << 3);
        *reinterpret_cast<uint4*>(&sm.Ks[rk * 128 + sw]) = pk[s];
        *reinterpret_cast<uint4*>(&sm.Vts[rk * 128 + sw]) = pv[s];
      }
      __syncthreads();
      if (kt + 1 < nst) {
        const int kn = (kt + 1) * 128;
#pragma unroll
        for (int s = 0; s < 4; ++s) {
          int id = s * 512 + t;
          int rk = id >> 4, ck = id & 15;
          pk[s] = *reinterpret_cast<const uint4*>(Kbase + (size_t)(kn + rk) * DK + (ck << 3));
          pv[s] = *reinterpret_cast<const uint4*>(VTbase + (size_t)rk * SEQ + kn + (ck << 3));
        }
      }

#pragma unroll
      for (int sub = 0; sub < 2; ++sub) {
        const int key0 = kt * 128 + sub * 64;

        // ---- S = Q K^T  (16 q-rows per wave) ----------------------------
        f32x4 sf[4] = {};
        __builtin_amdgcn_s_setprio(1);
#pragma unroll
        for (int ks = 0; ks < 4; ++ks) {
          int ra = wid * 16 + l16;
          bf16x8 aq = *reinterpret_cast<const bf16x8*>(
              &sm.Qs[ra * 128 + (((ks * 4 + lg) ^ (ra & 7)) << 3)]);
#pragma unroll
          for (int nj = 0; nj < 4; ++nj) {
            int rb = sub * 64 + nj * 16 + l16;
            bf16x8 bk = *reinterpret_cast<const bf16x8*>(
                &sm.Ks[rb * 128 + (((ks * 4 + lg) ^ (rb & 7)) << 3)]);
            sf[nj] = __builtin_amdgcn_mfma_f32_16x16x32_bf16(aq, bk, sf[nj], 0, 0, 0);
          }
        }
        __builtin_amdgcn_s_setprio(0);

        // ---- scale + causal mask ----------------------------------------
        const int qwbase = q0 + wid * 16;
        const bool need_mask = (key0 + 63) > qwbase;
#pragma unroll
        for (int nj = 0; nj < 4; ++nj) {
          int kcol = key0 + nj * 16 + l16;
#pragma unroll
          for (int r = 0; r < 4; ++r) {
            float v = sf[nj][r] * ATTN_SCALE;
            if (need_mask) {
              int qrow = qwbase + lg * 4 + r;
              if (kcol > qrow) v = -INFINITY;
            }
            sf[nj][r] = v;
          }
        }

        // ---- online softmax ---------------------------------------------
        float alpha[4];
#pragma unroll
        for (int r = 0; r < 4; ++r) {
          float m0 = fmaxf(fmaxf(sf[0][r], sf[1][r]), fmaxf(sf[2][r], sf[3][r]));
#pragma unroll
          for (int off = 1; off < 16; off <<= 1)
            m0 = fmaxf(m0, __shfl_xor(m0, off, 64));
          float mn = fmaxf(mrun[r], m0);
          alpha[r] = __expf(mrun[r] - mn);   // exp(-inf)=0 on first tile
          mrun[r] = mn;
        }
        float rs[4] = {0.f, 0.f, 0.f, 0.f};
#pragma unroll
        for (int nj = 0; nj < 4; ++nj) {
          int colb = nj * 16 + l16;
          int ch = colb >> 3, cb = colb & 7;
#pragma unroll
          for (int r = 0; r < 4; ++r) {
            float p = __expf(sf[nj][r] - mrun[r]);
            rs[r] += p;
            int prow = lg * 4 + r;
            sm.Ps[wid * 1024 + prow * 64 + ((ch ^ (prow & 7)) << 3) + cb] = f2bf(p);
          }
        }
#pragma unroll
        for (int r = 0; r < 4; ++r) {
          float s0 = rs[r];
#pragma unroll
          for (int off = 1; off < 16; off <<= 1)
            s0 += __shfl_xor(s0, off, 64);
          lrun[r] = lrun[r] * alpha[r] + s0;
        }
#pragma unroll
        for (int dj = 0; dj < 8; ++dj)
#pragma unroll
          for (int r = 0; r < 4; ++r) accO[dj][r] *= alpha[r];

        // ---- PV ---------------------------------------------------------
        __builtin_amdgcn_s_setprio(1);
#pragma unroll
        for (int ks = 0; ks < 2; ++ks) {
          bf16x8 ap = *reinterpret_cast<const bf16x8*>(
              &sm.Ps[wid * 1024 + l16 * 64 + (((ks * 4 + lg) ^ (l16 & 7)) << 3)]);
#pragma unroll
          for (int dj = 0; dj < 8; ++dj) {
            int rv = dj * 16 + l16;
            int c = sub * 8 + ks * 4 + lg;
            bf16x8 bv = *reinterpret_cast<const bf16x8*>(
                &sm.Vts[rv * 128 + ((c ^ (rv & 7)) << 3)]);
            accO[dj] = __builtin_amdgcn_mfma_f32_16x16x32_bf16(ap, bv, accO[dj], 0, 0, 0);
          }
        }
        __builtin_amdgcn_s_setprio(0);
      }
    }

    // ---- epilogue: reuse (dead) Ks as per-wave 16x128 transpose tile ----
    __syncthreads();   // all waves done reading Ks/Vts
    unsigned short* Pw = sm.Ks + wid * 2048;
    float inv[4];
#pragma unroll
    for (int r = 0; r < 4; ++r) inv[r] = 1.0f / lrun[r];
#pragma unroll
    for (int dj = 0; dj < 8; ++dj)
#pragma unroll
      for (int r = 0; r < 4; ++r)
        Pw[(lg * 4 + r) * 128 + dj * 16 + l16] = f2bf(accO[dj][r] * inv[r]);
    // same-wave write->read; compiler inserts lgkmcnt
#pragma unroll
    for (int ps = 0; ps < 4; ++ps) {
      int row = ps * 4 + lg;               // 0..15
      uint4 v = *reinterpret_cast<const uint4*>(&Pw[row * 128 + l16 * 8]);
      int qpos = q0 + wid * 16 + row;
      *reinterpret_cast<uint4*>(
          &AO[((size_t)(b * SEQ + qpos)) * DIM + h * DK + l16 * 8]) = v;
    }
    __syncthreads();   // protect Ks before next half restages
  }
}

// ---------------------------------------------------------------------------
extern "C" void kernel_launch(void* const* d_in, const int* in_sizes, int n_in,
                              void* d_out, int out_size, void* d_ws, size_t ws_size,
                              hipStream_t stream) {
  const float* x  = (const float*)d_in[0];
  const float* wq = (const float*)d_in[1];
  const float* wk = (const float*)d_in[2];
  const float* wv = (const float*)d_in[3];
  const float* wo = (const float*)d_in[4];

  // Outputs are FLOAT32: out [B,S,DIM], K [B,H,S,DK], V [B,H,S,DK].
  float* outF = (float*)d_out;
  float* outK = outF + TSZ;
  float* outV = outF + 2 * TSZ;

  // bf16 Q/K copies live in the (dead until final GEMM) out[0] f32 slot.
  unsigned short* qb = (unsigned short*)outF;
  unsigned short* kb = qb + TSZ;

  // ws (bf16 elems), total 2*TSZ + WSZ = 41.9 MB (proven footprint):
  //  xb  [0,TSZ)        converted x; later VT
  //  aop [TSZ,2TSZ)     wkb/wvb before attn; AO after (QKV weights dead by then)
  //  wb  [2TSZ,+WSZ)    wq (then wo) bf16
  unsigned short* xb  = (unsigned short*)d_ws;
  unsigned short* aop = xb + TSZ;
  unsigned short* wb  = xb + 2 * TSZ;
  unsigned short* wkb = aop;                    // first half of aop
  unsigned short* wvb = aop + WSZ;              // second half of aop
  unsigned short* vtb = xb;                     // VT over xb (x dead post-QKV)

  dim3 blk(256);
  const int cvtW = (int)(WSZ / 2048), n8W = (int)(WSZ / 8);

  cvt_f32_bf16<<<dim3((int)(TSZ / 2048)), blk, 0, stream>>>(x, xb, (int)(TSZ / 8));
  cvt3_f32_bf16<<<dim3(cvtW, 1, 3), blk, 0, stream>>>(wq, wk, wv, wb, wkb, wvb, n8W);

  gemm_qkv<<<dim3(16, 32, 3), blk, 0, stream>>>(xb, wb, wkb, wvb,
                                                qb, kb, outK, outV);

  vtrans<<<dim3(32, 32), blk, 0, stream>>>(outV, vtb);                // VT bf16

  attn_fused<<<dim3(32, 8), dim3(512), 0, stream>>>(qb, kb, vtb, aop);

  cvt_f32_bf16<<<dim3(cvtW), blk, 0, stream>>>(wo, wb, n8W);
  gemm_wo<<<dim3(16, 32), blk, 0, stream>>>(aop, wb, outF);           // final f32
}

// Round 22
// 317.964 us; speedup vs baseline: 1.0156x; 1.0148x over previous
//
#include <hip/hip_runtime.h>
#include <stdint.h>

typedef __bf16 bf16x8 __attribute__((ext_vector_type(8)));
typedef float f32x4 __attribute__((ext_vector_type(4)));

#define DEV __device__ __forceinline__
#define CAST_G(p) (const __attribute__((address_space(1))) unsigned int*)(p)
#define CAST_L(p) (__attribute__((address_space(3))) unsigned int*)(p)

constexpr int SEQ = 2048;
constexpr int DIM = 2048;
constexpr int NH  = 16;
constexpr int DK  = 128;
constexpr int BATCH = 2;
constexpr size_t TSZ = (size_t)BATCH * SEQ * DIM;   // 8388608 elements
constexpr size_t WSZ = (size_t)DIM * DIM;           // 4194304 elements per weight
constexpr float ATTN_SCALE = 0.08838834764831845f;  // 1/sqrt(128)

DEV unsigned short f2bf(float f) {
  unsigned int u = __float_as_uint(f);
  unsigned int r = (u + 0x7fffu + ((u >> 16) & 1u)) >> 16;
  return (unsigned short)r;
}

// ---------------------------------------------------------------------------
// fp32 -> bf16 (RTNE), 8 elements/thread, vectorized.
// ---------------------------------------------------------------------------
__global__ __launch_bounds__(256)
void cvt_f32_bf16(const float* __restrict__ src, unsigned short* __restrict__ dst,
                  int n8) {
  int i = blockIdx.x * 256 + threadIdx.x;
  if (i >= n8) return;
  float4 a = *reinterpret_cast<const float4*>(src + (size_t)i * 8);
  float4 b = *reinterpret_cast<const float4*>(src + (size_t)i * 8 + 4);
  unsigned short o[8];
  o[0] = f2bf(a.x); o[1] = f2bf(a.y); o[2] = f2bf(a.z); o[3] = f2bf(a.w);
  o[4] = f2bf(b.x); o[5] = f2bf(b.y); o[6] = f2bf(b.z); o[7] = f2bf(b.w);
  *reinterpret_cast<uint4*>(dst + (size_t)i * 8) = *reinterpret_cast<const uint4*>(o);
}

// Batched 3-weight conversion (z selects source/dest).
__global__ __launch_bounds__(256)
void cvt3_f32_bf16(const float* __restrict__ s0, const float* __restrict__ s1,
                   const float* __restrict__ s2,
                   unsigned short* __restrict__ d0, unsigned short* __restrict__ d1,
                   unsigned short* __restrict__ d2, int n8) {
  const float* src = (blockIdx.z == 0) ? s0 : (blockIdx.z == 1) ? s1 : s2;
  unsigned short* dst = (blockIdx.z == 0) ? d0 : (blockIdx.z == 1) ? d1 : d2;
  int i = blockIdx.x * 256 + threadIdx.x;
  if (i >= n8) return;
  float4 a = *reinterpret_cast<const float4*>(src + (size_t)i * 8);
  float4 b = *reinterpret_cast<const float4*>(src + (size_t)i * 8 + 4);
  unsigned short o[8];
  o[0] = f2bf(a.x); o[1] = f2bf(a.y); o[2] = f2bf(a.z); o[3] = f2bf(a.w);
  o[4] = f2bf(b.x); o[5] = f2bf(b.y); o[6] = f2bf(b.z); o[7] = f2bf(b.w);
  *reinterpret_cast<uint4*>(dst + (size_t)i * 8) = *reinterpret_cast<const uint4*>(o);
}

// ---------------------------------------------------------------------------
// Shared GEMM core: C[M,Nc] = A[M,K] * W[Nc,K]^T (row-major, bf16, fp32 acc)
// 128x128 tile, BK=64, 4 waves (2x2).  Staging via global_load_lds(16B) with
// PRE-SWIZZLED SOURCE (involution c8^=(r&7)); LDS dest linear; reads XOR'd.
// ---------------------------------------------------------------------------
DEV void gemm_core(const unsigned short* __restrict__ A,
                   const unsigned short* __restrict__ W,
                   unsigned short* As, unsigned short* Bs,
                   int row0, int col0, int t, int wid, int wr, int wc,
                   int l16, int lg, f32x4 (&acc)[4][4]) {
  const int srow = t >> 3;                         // 0..31
  const int scol = ((t & 7) ^ (srow & 7)) << 3;    // pre-swizzled src elem off
  const unsigned short* Asrc = A + (size_t)(row0 + srow) * DIM + scol;
  const unsigned short* Wsrc = W + (size_t)(col0 + srow) * DIM + scol;

  for (int k0 = 0; k0 < DIM; k0 += 64) {
    __syncthreads();
#pragma unroll
    for (int i = 0; i < 4; ++i) {
      __builtin_amdgcn_global_load_lds(CAST_G(Asrc + (size_t)i * 32 * DIM + k0),
                                       CAST_L(As + i * 2048 + wid * 512), 16, 0, 0);
      __builtin_amdgcn_global_load_lds(CAST_G(Wsrc + (size_t)i * 32 * DIM + k0),
                                       CAST_L(Bs + i * 2048 + wid * 512), 16, 0, 0);
    }
    __syncthreads();
#pragma unroll
    for (int ks = 0; ks < 2; ++ks) {
      bf16x8 af[4], bfr[4];
#pragma unroll
      for (int i = 0; i < 4; ++i) {
        int ra = wr + i * 16 + l16;
        af[i] = *reinterpret_cast<const bf16x8*>(&As[ra * 64 + (((ks * 4 + lg) ^ (ra & 7)) << 3)]);
        int rb = wc + i * 16 + l16;
        bfr[i] = *reinterpret_cast<const bf16x8*>(&Bs[rb * 64 + (((ks * 4 + lg) ^ (rb & 7)) << 3)]);
      }
#pragma unroll
      for (int i = 0; i < 4; ++i)
#pragma unroll
        for (int j = 0; j < 4; ++j)
          acc[i][j] = __builtin_amdgcn_mfma_f32_16x16x32_bf16(af[i], bfr[j], acc[i][j], 0, 0, 0);
    }
  }
}

// ---------------------------------------------------------------------------
// Merged QKV projection: blockIdx.z selects {wq,wk,wv}.
// z=0: RoPE -> scatter bf16 Q.  z=1: RoPE -> scatter f32 K + bf16 K.
// z=2: scatter f32 V.
// ---------------------------------------------------------------------------
__global__ __launch_bounds__(256, 2)
void gemm_qkv(const unsigned short* __restrict__ A,
              const unsigned short* __restrict__ W0,
              const unsigned short* __restrict__ W1,
              const unsigned short* __restrict__ W2,
              unsigned short* __restrict__ Qb,
              unsigned short* __restrict__ Kb,
              float* __restrict__ Kf,
              float* __restrict__ Vf) {
  __shared__ __align__(16) unsigned short As[128 * 64];
  __shared__ __align__(16) unsigned short Bs[128 * 64];

  const int t = threadIdx.x;
  const int lane = t & 63;
  const int wid = t >> 6;
  const int wr = (wid >> 1) << 6;
  const int wc = (wid & 1) << 6;
  const int l16 = lane & 15, lg = lane >> 4;
  const int row0 = blockIdx.y * 128;
  const int col0 = blockIdx.x * 128;
  const int z = blockIdx.z;
  const unsigned short* W = (z == 0) ? W0 : ((z == 1) ? W1 : W2);

  f32x4 acc[4][4] = {};
  gemm_core(A, W, As, Bs, row0, col0, t, wid, wr, wc, l16, lg, acc);

#pragma unroll
  for (int j = 0; j < 4; ++j) {
    int colg = col0 + wc + j * 16 + l16;
    int jj = (colg >> 1) & 63;
    float invf = __expf((float)jj * -0.14391156831212787f);  // 10000^(-jj/64)
#pragma unroll
    for (int i = 0; i < 4; ++i) {
#pragma unroll
      for (int r = 0; r < 4; ++r) {
        int rowg = row0 + wr + i * 16 + lg * 4 + r;
        float v = acc[i][j][r];
        float outv;
        if (z < 2) {
          float p = __shfl_xor(v, 1, 64);
          int pos = rowg & (SEQ - 1);
          float ang = (float)pos * invf;
          float sn, cs;
          __sincosf(ang, &sn, &cs);
          outv = (colg & 1) ? fmaf(p, sn, v * cs) : fmaf(v, cs, -(p * sn));
        } else {
          outv = v;
        }
        int b = rowg >> 11, pos = rowg & (SEQ - 1);
        int h = colg >> 7, d = colg & (DK - 1);
        size_t idx = (((size_t)(b * NH + h)) * SEQ + pos) * DK + d;
        if (z == 0) Qb[idx] = f2bf(outv);
        else if (z == 1) { Kf[idx] = outv; Kb[idx] = f2bf(outv); }
        else Vf[idx] = outv;
      }
    }
  }
}

// ---------------------------------------------------------------------------
// WO projection: plain row-major f32 store.
// ---------------------------------------------------------------------------
__global__ __launch_bounds__(256, 2)
void gemm_wo(const unsigned short* __restrict__ A,
             const unsigned short* __restrict__ W,
             float* __restrict__ Df) {
  __shared__ __align__(16) unsigned short As[128 * 64];
  __shared__ __align__(16) unsigned short Bs[128 * 64];

  const int t = threadIdx.x;
  const int lane = t & 63;
  const int wid = t >> 6;
  const int wr = (wid >> 1) << 6;
  const int wc = (wid & 1) << 6;
  const int l16 = lane & 15, lg = lane >> 4;
  const int row0 = blockIdx.y * 128;
  const int col0 = blockIdx.x * 128;

  f32x4 acc[4][4] = {};
  gemm_core(A, W, As, Bs, row0, col0, t, wid, wr, wc, l16, lg, acc);

#pragma unroll
  for (int i = 0; i < 4; ++i)
#pragma unroll
    for (int j = 0; j < 4; ++j) {
      int colg = col0 + wc + j * 16 + l16;
#pragma unroll
      for (int r = 0; r < 4; ++r) {
        int rowg = row0 + wr + i * 16 + lg * 4 + r;
        Df[(size_t)rowg * DIM + colg] = acc[i][j][r];
      }
    }
}

// ---------------------------------------------------------------------------
// V^T builder: V [B,H,S,DK] f32 -> VT [B,H,DK,S] bf16
// ---------------------------------------------------------------------------
__global__ __launch_bounds__(256, 2)
void vtrans(const float* __restrict__ V, unsigned short* __restrict__ VT) {
  __shared__ float vs[64 * 128];  // 32KB [pos][d]
  const int t = threadIdx.x;
  const int bh = blockIdx.y;
  const int p0 = blockIdx.x * 64;
  const float* src = V + ((size_t)bh * SEQ + p0) * DK;
#pragma unroll
  for (int s = 0; s < 8; ++s) {
    int id = s * 256 + t;
    *reinterpret_cast<float4*>(&vs[id * 4]) = *reinterpret_cast<const float4*>(&src[id * 4]);
  }
  __syncthreads();
  const int w = t >> 6, l = t & 63;
  unsigned short* dstb = VT + (size_t)bh * DK * SEQ + p0;
#pragma unroll
  for (int it = 0; it < 4; ++it) {
    int d = w * 32 + (it & 1) * 16 + (l & 15);
    int kc = (it >> 1) * 4 + (l >> 4);
    unsigned short tmp[8];
#pragma unroll
    for (int j = 0; j < 8; ++j) tmp[j] = f2bf(vs[(kc * 8 + j) * DK + d]);
    *reinterpret_cast<uint4*>(&dstb[(size_t)d * SEQ + kc * 8]) =
        *reinterpret_cast<const uint4*>(tmp);
  }
}

// ---------------------------------------------------------------------------
// Fused causal flash attention — DOUBLE-BUFFERED K/V LDS (KVBLK=64).
// 512 thr / 8 waves, one block per (bh, pair).  Pair {15-pj, pj}:
// nst = 2(qt+1) >= 2 iters of 64 keys; ONE barrier per iter (dbuf orders
// both hazards).  Tile t+1's regs ds_written to buf[(t+1)&1] BEFORE
// compute of tile t (interleaves under lgkmcnt); tile t+2 loads issue
// alongside.  Static reg sets E(ven)/O(dd) — no runtime-indexed arrays.
// Grid (bh=32, pj=8): lin%8 = bh%8 -> XCD locality.
// LDS 112KB: Qs 32 + 2x(Ks 16 + Vts 16) + Ps 16.
// ---------------------------------------------------------------------------
struct __align__(16) AttnSmem {
  unsigned short Qs[128 * 128];      // 32KB [q][dk], swizzled
  unsigned short Ks[2][64 * 128];    // 2x16KB [key][dk], swizzled (epi reuse)
  unsigned short Vts[2][128 * 64];   // 2x16KB [d][key], swizzled
  unsigned short Ps[8 * 16 * 64];    // 16KB per-wave P, swizzled
};

__global__ __launch_bounds__(512, 1)
void attn_fused(const unsigned short* __restrict__ Q,
                const unsigned short* __restrict__ K,
                const unsigned short* __restrict__ VT,
                unsigned short* __restrict__ AO) {
  __shared__ AttnSmem sm;
  const int t = threadIdx.x;          // 0..511
  const int lane = t & 63;
  const int wid = t >> 6;             // 0..7
  const int l16 = lane & 15, lg = lane >> 4;
  const int bh = blockIdx.x;          // 0..31  (lin%8 = bh%8 -> XCD locality)
  const int pj = blockIdx.y;          // 0..7 pair id
  const int b = bh >> 4, h = bh & 15;

  const unsigned short* Kbase = K + (size_t)bh * SEQ * DK;
  const unsigned short* VTbase = VT + (size_t)bh * DK * SEQ;

  // staging thread geometry (constant):
  const int rk = t >> 4, ck = t & 15;          // K: rows 0..31 (+32/s), 16 chunks
  const int rv = t >> 3, cv = t & 7;           // VT: rows 0..63 (+64/s), 8 chunks
  const int swk = (ck ^ (rk & 7)) << 3;
  const int swk2 = (ck ^ ((rk + 32) & 7)) << 3;
  const int swv = (cv ^ (rv & 7)) << 3;
  const int swv2 = (cv ^ ((rv + 64) & 7)) << 3;

#define LOAD_SET(PK, PV, KEYOFF)                                               \
  {                                                                            \
    const int kn_ = (KEYOFF);                                                  \
    PK[0] = *reinterpret_cast<const uint4*>(Kbase + (size_t)(kn_ + rk) * DK + (ck << 3));      \
    PK[1] = *reinterpret_cast<const uint4*>(Kbase + (size_t)(kn_ + rk + 32) * DK + (ck << 3)); \
    PV[0] = *reinterpret_cast<const uint4*>(VTbase + (size_t)rv * SEQ + kn_ + (cv << 3));      \
    PV[1] = *reinterpret_cast<const uint4*>(VTbase + (size_t)(rv + 64) * SEQ + kn_ + (cv << 3)); \
  }

#define WRITE_SET(PK, PV, BUF)                                                 \
  {                                                                            \
    *reinterpret_cast<uint4*>(&sm.Ks[BUF][rk * 128 + swk]) = PK[0];            \
    *reinterpret_cast<uint4*>(&sm.Ks[BUF][(rk + 32) * 128 + swk2]) = PK[1];    \
    *reinterpret_cast<uint4*>(&sm.Vts[BUF][rv * 64 + swv]) = PV[0];            \
    *reinterpret_cast<uint4*>(&sm.Vts[BUF][(rv + 64) * 64 + swv2]) = PV[1];    \
  }

  for (int half = 0; half < 2; ++half) {
    const int qt = half ? pj : (15 - pj);
    const int q0 = qt * 128;
    const int nst = 2 * (qt + 1);     // 64-key iters, always >= 2
    const unsigned short* Qbase = Q + ((size_t)bh * SEQ + q0) * DK;

    // stage Q tile [128][128]: 16 chunks/row, swizzle c^(r&7)
#pragma unroll
    for (int s = 0; s < 4; ++s) {
      int id = s * 512 + t;
      int r = id >> 4, c = id & 15;
      uint4 v = *reinterpret_cast<const uint4*>(Qbase + (size_t)r * DK + (c << 3));
      *reinterpret_cast<uint4*>(&sm.Qs[r * 128 + ((c ^ (r & 7)) << 3)]) = v;
    }

    f32x4 accO[8] = {};
    float mrun[4], lrun[4];
#pragma unroll
    for (int r = 0; r < 4; ++r) { mrun[r] = -INFINITY; lrun[r] = 0.f; }

    // even/odd register sets: E stages even tiles, O stages odd tiles.
    uint4 pkE[2], pvE[2], pkO[2], pvO[2];
    LOAD_SET(pkE, pvE, 0)            // tile 0
    LOAD_SET(pkO, pvO, 64)           // tile 1 (nst >= 2 always)
    WRITE_SET(pkE, pvE, 0)           // buf0 <- tile 0
    __syncthreads();                 // buf0 ready

    for (int kt = 0; kt < nst; ++kt) {
      const int key0 = kt * 64;
      const int cur = kt & 1;

      // write next tile's buffer + issue tile kt+2 loads (interleave w/ compute)
      if (kt + 1 < nst) {
        if (cur == 0) { WRITE_SET(pkO, pvO, 1) }
        else          { WRITE_SET(pkE, pvE, 0) }
      }
      if (kt + 2 < nst) {
        if (cur == 0) { LOAD_SET(pkE, pvE, (kt + 2) * 64) }
        else          { LOAD_SET(pkO, pvO, (kt + 2) * 64) }
      }

      const unsigned short* KsCur = sm.Ks[cur];
      const unsigned short* VtsCur = sm.Vts[cur];

      // ---- S = Q K^T  (16 q-rows per wave) ------------------------------
      f32x4 sf[4] = {};
      __builtin_amdgcn_s_setprio(1);
#pragma unroll
      for (int ks = 0; ks < 4; ++ks) {
        int ra = wid * 16 + l16;
        bf16x8 aq = *reinterpret_cast<const bf16x8*>(
            &sm.Qs[ra * 128 + (((ks * 4 + lg) ^ (ra & 7)) << 3)]);
#pragma unroll
        for (int nj = 0; nj < 4; ++nj) {
          int rb = nj * 16 + l16;
          bf16x8 bk = *reinterpret_cast<const bf16x8*>(
              &KsCur[rb * 128 + (((ks * 4 + lg) ^ (rb & 7)) << 3)]);
          sf[nj] = __builtin_amdgcn_mfma_f32_16x16x32_bf16(aq, bk, sf[nj], 0, 0, 0);
        }
      }
      __builtin_amdgcn_s_setprio(0);

      // ---- scale + causal mask ------------------------------------------
      const int qwbase = q0 + wid * 16;
      const bool need_mask = (key0 + 63) > qwbase;
#pragma unroll
      for (int nj = 0; nj < 4; ++nj) {
        int kcol = key0 + nj * 16 + l16;
#pragma unroll
        for (int r = 0; r < 4; ++r) {
          float v = sf[nj][r] * ATTN_SCALE;
          if (need_mask) {
            int qrow = qwbase + lg * 4 + r;
            if (kcol > qrow) v = -INFINITY;
          }
          sf[nj][r] = v;
        }
      }

      // ---- online softmax -----------------------------------------------
      float alpha[4];
#pragma unroll
      for (int r = 0; r < 4; ++r) {
        float m0 = fmaxf(fmaxf(sf[0][r], sf[1][r]), fmaxf(sf[2][r], sf[3][r]));
#pragma unroll
        for (int off = 1; off < 16; off <<= 1)
          m0 = fmaxf(m0, __shfl_xor(m0, off, 64));
        float mn = fmaxf(mrun[r], m0);
        alpha[r] = __expf(mrun[r] - mn);   // exp(-inf)=0 on first tile
        mrun[r] = mn;
      }
      float rs[4] = {0.f, 0.f, 0.f, 0.f};
#pragma unroll
      for (int nj = 0; nj < 4; ++nj) {
        int colb = nj * 16 + l16;
        int ch = colb >> 3, cb = colb & 7;
#pragma unroll
        for (int r = 0; r < 4; ++r) {
          float p = __expf(sf[nj][r] - mrun[r]);
          rs[r] += p;
          int prow = lg * 4 + r;
          sm.Ps[wid * 1024 + prow * 64 + ((ch ^ (prow & 7)) << 3) + cb] = f2bf(p);
        }
      }
#pragma unroll
      for (int r = 0; r < 4; ++r) {
        float s0 = rs[r];
#pragma unroll
        for (int off = 1; off < 16; off <<= 1)
          s0 += __shfl_xor(s0, off, 64);
        lrun[r] = lrun[r] * alpha[r] + s0;
      }
#pragma unroll
      for (int dj = 0; dj < 8; ++dj)
#pragma unroll
        for (int r = 0; r < 4; ++r) accO[dj][r] *= alpha[r];

      // ---- PV -----------------------------------------------------------
      __builtin_amdgcn_s_setprio(1);
#pragma unroll
      for (int ks = 0; ks < 2; ++ks) {
        bf16x8 ap = *reinterpret_cast<const bf16x8*>(
            &sm.Ps[wid * 1024 + l16 * 64 + (((ks * 4 + lg) ^ (l16 & 7)) << 3)]);
#pragma unroll
        for (int dj = 0; dj < 8; ++dj) {
          int rvv = dj * 16 + l16;
          bf16x8 bv = *reinterpret_cast<const bf16x8*>(
              &VtsCur[rvv * 64 + (((ks * 4 + lg) ^ (rvv & 7)) << 3)]);
          accO[dj] = __builtin_amdgcn_mfma_f32_16x16x32_bf16(ap, bv, accO[dj], 0, 0, 0);
        }
      }
      __builtin_amdgcn_s_setprio(0);

      __syncthreads();   // buf[cur^1] writes done; buf[cur] reads done
    }

    // ---- epilogue: per-wave 16x128 transpose in (dead) Ks region --------
    unsigned short* Pw = &sm.Ks[0][0] + wid * 2048;   // 8 x 4KB = Ks[0]+Ks[1]
    float inv[4];
#pragma unroll
    for (int r = 0; r < 4; ++r) inv[r] = 1.0f / lrun[r];
#pragma unroll
    for (int dj = 0; dj < 8; ++dj)
#pragma unroll
      for (int r = 0; r < 4; ++r)
        Pw[(lg * 4 + r) * 128 + dj * 16 + l16] = f2bf(accO[dj][r] * inv[r]);
    // same-wave write->read; compiler inserts lgkmcnt
#pragma unroll
    for (int ps = 0; ps < 4; ++ps) {
      int row = ps * 4 + lg;               // 0..15
      uint4 v = *reinterpret_cast<const uint4*>(&Pw[row * 128 + l16 * 8]);
      int qpos = q0 + wid * 16 + row;
      *reinterpret_cast<uint4*>(
          &AO[((size_t)(b * SEQ + qpos)) * DIM + h * DK + l16 * 8]) = v;
    }
    __syncthreads();   // protect Ks before next half restages
  }
#undef LOAD_SET
#undef WRITE_SET
}

// ---------------------------------------------------------------------------
extern "C" void kernel_launch(void* const* d_in, const int* in_sizes, int n_in,
                              void* d_out, int out_size, void* d_ws, size_t ws_size,
                              hipStream_t stream) {
  const float* x  = (const float*)d_in[0];
  const float* wq = (const float*)d_in[1];
  const float* wk = (const float*)d_in[2];
  const float* wv = (const float*)d_in[3];
  const float* wo = (const float*)d_in[4];

  // Outputs are FLOAT32: out [B,S,DIM], K [B,H,S,DK], V [B,H,S,DK].
  float* outF = (float*)d_out;
  float* outK = outF + TSZ;
  float* outV = outF + 2 * TSZ;

  // bf16 Q/K copies live in the (dead until final GEMM) out[0] f32 slot.
  unsigned short* qb = (unsigned short*)outF;
  unsigned short* kb = qb + TSZ;

  // ws (bf16 elems), total 2*TSZ + WSZ = 41.9 MB (proven footprint):
  unsigned short* xb  = (unsigned short*)d_ws;
  unsigned short* aop = xb + TSZ;
  unsigned short* wb  = xb + 2 * TSZ;
  unsigned short* wkb = aop;                    // first half of aop
  unsigned short* wvb = aop + WSZ;              // second half of aop
  unsigned short* vtb = xb;                     // VT over xb (x dead post-QKV)

  dim3 blk(256);
  const int cvtW = (int)(WSZ / 2048), n8W = (int)(WSZ / 8);

  cvt_f32_bf16<<<dim3((int)(TSZ / 2048)), blk, 0, stream>>>(x, xb, (int)(TSZ / 8));
  cvt3_f32_bf16<<<dim3(cvtW, 1, 3), blk, 0, stream>>>(wq, wk, wv, wb, wkb, wvb, n8W);

  gemm_qkv<<<dim3(16, 32, 3), blk, 0, stream>>>(xb, wb, wkb, wvb,
                                                qb, kb, outK, outV);

  vtrans<<<dim3(32, 32), blk, 0, stream>>>(outV, vtb);                // VT bf16

  attn_fused<<<dim3(32, 8), dim3(512), 0, stream>>>(qb, kb, vtb, aop);

  cvt_f32_bf16<<<dim3(cvtW), blk, 0, stream>>>(wo, wb, n8W);
  gemm_wo<<<dim3(16, 32), blk, 0, stream>>>(aop, wb, outF);           // final f32
}